// Round 1
// baseline (294.349 us; speedup 1.0000x reference)
//
#include <hip/hip_runtime.h>
#include <cstdint>
#include <cstddef>

// RNNT joiner: logits[b,t,u,v] = sum_j tanh(E[b,t,j]+P[b,u,j]) * out_w[v,j] + out_b[v]
// B=4 T=256 U=64 D=512 J=640 V=1024.  M = 65536 rows (b,t,u), N=1024, K=640.
//
// ws layout:
//   E  : float [1024][640]            @ 0         (2,621,440 B)
//   P  : float [ 256][640]            @ 2,621,440 (  655,360 B)
//   Wb : bf16 blocked [8][10][8192]   @ 3,276,800 (1,310,720 B)  (pre-swizzled)

typedef __attribute__((ext_vector_type(8))) __bf16 bf16x8;
typedef __attribute__((ext_vector_type(4))) float f32x4;

// XOR swizzle within a [row][64] bf16 tile (row stride 128B): spread 8-row
// groups across all 32 banks. kElem must be 8-aligned for 16B accesses.
__device__ __forceinline__ int swz(int row, int kElem) {
  return (row << 6) + (kElem ^ ((row & 7) << 3));
}

__device__ __forceinline__ float fast_tanh(float x) {
  float e = __expf(2.0f * x);                     // exp2-based native exp
  return 1.0f - 2.0f * __builtin_amdgcn_rcpf(e + 1.0f);
}

// ---------------------------------------------------------------------------
// Stage 1: C[M][N] = A[M][512] . W[N][512]^T + bias   (fp32 in/out, bf16 MFMA)
// grid = (M/128) * (N/128), 256 threads, tile 128x128, BK=64.
// ---------------------------------------------------------------------------
__global__ __launch_bounds__(256) void proj_kernel(
    const float* __restrict__ A, const float* __restrict__ W,
    const float* __restrict__ bias, float* __restrict__ C, int N)
{
  __shared__ __align__(16) __bf16 As[128 * 64];
  __shared__ __align__(16) __bf16 Bs[128 * 64];
  const int tid  = threadIdx.x;
  const int ntile = N >> 7;
  const int mt = blockIdx.x / ntile, nt = blockIdx.x % ntile;
  const int r = tid & 127, half = tid >> 7;
  const int lane = tid & 63, wv = tid >> 6;
  const int wm = wv >> 1, wn = wv & 1;

  const float* arow = A + (size_t)(mt * 128 + r) * 512 + half * 32;
  const float* wrow = W + (size_t)(nt * 128 + r) * 512 + half * 32;

  f32x4 acc[4][4] = {};

  for (int k0 = 0; k0 < 512; k0 += 64) {
#pragma unroll
    for (int s = 0; s < 4; ++s) {
      f32x4 a0 = *(const f32x4*)(arow + k0 + s * 8);
      f32x4 a1 = *(const f32x4*)(arow + k0 + s * 8 + 4);
      f32x4 w0 = *(const f32x4*)(wrow + k0 + s * 8);
      f32x4 w1 = *(const f32x4*)(wrow + k0 + s * 8 + 4);
      bf16x8 za, zw;
#pragma unroll
      for (int j = 0; j < 4; ++j) {
        za[j] = (__bf16)a0[j]; za[4 + j] = (__bf16)a1[j];
        zw[j] = (__bf16)w0[j]; zw[4 + j] = (__bf16)w1[j];
      }
      const int kk = half * 32 + s * 8;
      *(bf16x8*)&As[swz(r, kk)] = za;
      *(bf16x8*)&Bs[swz(r, kk)] = zw;
    }
    __syncthreads();
#pragma unroll
    for (int kk = 0; kk < 2; ++kk) {
      bf16x8 af[4], bfr[4];
#pragma unroll
      for (int i = 0; i < 4; ++i) {
        af[i]  = *(const bf16x8*)&As[swz(wm * 64 + i * 16 + (lane & 15), kk * 32 + (lane >> 4) * 8)];
        bfr[i] = *(const bf16x8*)&Bs[swz(wn * 64 + i * 16 + (lane & 15), kk * 32 + (lane >> 4) * 8)];
      }
#pragma unroll
      for (int mi = 0; mi < 4; ++mi)
#pragma unroll
        for (int ni = 0; ni < 4; ++ni)
          acc[mi][ni] = __builtin_amdgcn_mfma_f32_16x16x32_bf16(af[mi], bfr[ni], acc[mi][ni], 0, 0, 0);
    }
    __syncthreads();
  }

  const int rowbase = mt * 128 + wm * 64;
  const int colbase = nt * 128 + wn * 64;
#pragma unroll
  for (int ni = 0; ni < 4; ++ni) {
    const int col = colbase + ni * 16 + (lane & 15);
    const float bb = bias[col];
#pragma unroll
    for (int mi = 0; mi < 4; ++mi) {
      const int row = rowbase + mi * 16 + (lane >> 4) * 4;
#pragma unroll
      for (int rg = 0; rg < 4; ++rg)
        C[(size_t)(row + rg) * N + col] = acc[mi][ni][rg] + bb;
    }
  }
}

// ---------------------------------------------------------------------------
// Stage 1b: out_w fp32 [1024][640] -> bf16, blocked [nb(8)][kb(10)][8192],
// each 8192-elem block pre-swizzled so a linear LDS copy yields swz layout.
// ---------------------------------------------------------------------------
__global__ __launch_bounds__(256) void convw_kernel(
    const float* __restrict__ Wsrc, __bf16* __restrict__ Wb)
{
  const int gid = blockIdx.x * 256 + threadIdx.x;  // 81920 total (1024*80)
  const int v  = gid / 80;
  const int j8 = gid % 80;
  f32x4 w0 = *(const f32x4*)(Wsrc + (size_t)v * 640 + j8 * 8);
  f32x4 w1 = *(const f32x4*)(Wsrc + (size_t)v * 640 + j8 * 8 + 4);
  bf16x8 z;
#pragma unroll
  for (int j = 0; j < 4; ++j) { z[j] = (__bf16)w0[j]; z[4 + j] = (__bf16)w1[j]; }
  const int nb = v >> 7, rr = v & 127;
  const int kb = j8 >> 3, kk = (j8 & 7) * 8;
  *(bf16x8*)(Wb + ((size_t)(nb * 10 + kb) << 13) + swz(rr, kk)) = z;
}

// ---------------------------------------------------------------------------
// Stage 2 (main): fused tanh(E+P) x Wb GEMM.
// grid = 512*8 blocks; block tile 128(M) x 128(N), BK=64, 4 waves (2x2),
// each wave 64x64 via 4x4 frags of mfma_f32_16x16x32_bf16.
// M row = ((b*256 + t)*64 + u); a 128-row tile = fixed b, 2 t's, all 64 u's.
// ---------------------------------------------------------------------------
__global__ __launch_bounds__(256) void joiner_main(
    const float* __restrict__ E, const float* __restrict__ P,
    const __bf16* __restrict__ Wb, const float* __restrict__ outb,
    float* __restrict__ out)
{
  __shared__ __align__(16) __bf16 As[128 * 64];
  __shared__ __align__(16) __bf16 Bs[128 * 64];
  const int tid = threadIdx.x;
  const int nt = blockIdx.x & 7;
  const int mt = blockIdx.x >> 3;
  const int row0 = mt << 7;
  const int b  = row0 >> 14;          // 16384 rows per batch
  const int t0 = (row0 >> 6) & 255;   // row r in tile: t = t0 + (r>>6), u = r&63
  const int r = tid & 127, half = tid >> 7;
  const int lane = tid & 63, wv = tid >> 6;
  const int wm = wv >> 1, wn = wv & 1;

  const float* ep = E + (size_t)((b << 8) + t0 + (r >> 6)) * 640 + half * 32;
  const float* pp = P + (size_t)((b << 6) + (r & 63)) * 640 + half * 32;
  const __bf16* wsrc = Wb + ((size_t)(nt * 10) << 13) + (tid << 3);

  f32x4 acc[4][4] = {};

  for (int kt = 0; kt < 10; ++kt) {
    const int k0 = kt << 6;
    // --- stage B: linear copy of pre-swizzled 16KB block ---
#pragma unroll
    for (int i = 0; i < 4; ++i) {
      bf16x8 wc = *(const bf16x8*)(wsrc + (kt << 13) + i * 2048);
      *(bf16x8*)&Bs[(i * 256 + tid) * 8] = wc;
    }
    // --- stage A: z = tanh(E + P), fp32 -> bf16, swizzled write ---
#pragma unroll
    for (int s = 0; s < 4; ++s) {
      f32x4 e0 = *(const f32x4*)(ep + k0 + s * 8);
      f32x4 e1 = *(const f32x4*)(ep + k0 + s * 8 + 4);
      f32x4 p0 = *(const f32x4*)(pp + k0 + s * 8);
      f32x4 p1 = *(const f32x4*)(pp + k0 + s * 8 + 4);
      bf16x8 z;
#pragma unroll
      for (int j = 0; j < 4; ++j) {
        z[j]     = (__bf16)fast_tanh(e0[j] + p0[j]);
        z[4 + j] = (__bf16)fast_tanh(e1[j] + p1[j]);
      }
      *(bf16x8*)&As[swz(r, half * 32 + s * 8)] = z;
    }
    __syncthreads();
#pragma unroll
    for (int kk = 0; kk < 2; ++kk) {
      bf16x8 af[4], bfr[4];
#pragma unroll
      for (int i = 0; i < 4; ++i) {
        af[i]  = *(const bf16x8*)&As[swz(wm * 64 + i * 16 + (lane & 15), kk * 32 + (lane >> 4) * 8)];
        bfr[i] = *(const bf16x8*)&Bs[swz(wn * 64 + i * 16 + (lane & 15), kk * 32 + (lane >> 4) * 8)];
      }
#pragma unroll
      for (int mi = 0; mi < 4; ++mi)
#pragma unroll
        for (int ni = 0; ni < 4; ++ni)
          acc[mi][ni] = __builtin_amdgcn_mfma_f32_16x16x32_bf16(af[mi], bfr[ni], acc[mi][ni], 0, 0, 0);
    }
    __syncthreads();
  }

  const int rowbase = row0 + wm * 64;
  const int colbase = (nt << 7) + wn * 64;
#pragma unroll
  for (int ni = 0; ni < 4; ++ni) {
    const int col = colbase + ni * 16 + (lane & 15);
    const float bb = outb[col];
#pragma unroll
    for (int mi = 0; mi < 4; ++mi) {
      const int row = rowbase + mi * 16 + (lane >> 4) * 4;
#pragma unroll
      for (int rg = 0; rg < 4; ++rg)
        out[(size_t)(row + rg) * 1024 + col] = acc[mi][ni][rg] + bb;
    }
  }
}

extern "C" void kernel_launch(void* const* d_in, const int* in_sizes, int n_in,
                              void* d_out, int out_size, void* d_ws, size_t ws_size,
                              hipStream_t stream) {
  const float* enc    = (const float*)d_in[0];
  const float* pred   = (const float*)d_in[1];
  const float* enc_w  = (const float*)d_in[2];
  const float* enc_b  = (const float*)d_in[3];
  const float* pred_w = (const float*)d_in[4];
  const float* pred_b = (const float*)d_in[5];
  const float* out_w  = (const float*)d_in[6];
  const float* out_b  = (const float*)d_in[7];
  float* out = (float*)d_out;

  char* ws = (char*)d_ws;
  float*  E  = (float*)(ws);                  // 1024*640 f32
  float*  P  = (float*)(ws + 2621440);        //  256*640 f32
  __bf16* Wb = (__bf16*)(ws + 3276800);       // 8*10*8192 bf16, pre-swizzled

  // E = enc @ enc_w^T + enc_b   (M=1024, N=640)
  proj_kernel<<<dim3(8 * 5), dim3(256), 0, stream>>>(enc, enc_w, enc_b, E, 640);
  // P = pred @ pred_w^T + pred_b (M=256, N=640)
  proj_kernel<<<dim3(2 * 5), dim3(256), 0, stream>>>(pred, pred_w, pred_b, P, 640);
  // Wb = bf16(out_w), blocked + swizzled
  convw_kernel<<<dim3(320), dim3(256), 0, stream>>>(out_w, Wb);
  // logits
  joiner_main<<<dim3(512 * 8), dim3(256), 0, stream>>>(E, P, Wb, out_b, out);
}

// Round 2
// 187.011 us; speedup vs baseline: 1.5740x; 1.5740x over previous
//
#include <hip/hip_runtime.h>
#include <cstdint>
#include <cstddef>

// RNNT joiner: logits[b,t,u,v] = sum_j tanh(E[b,t,j]+P[b,u,j]) * out_w[v,j] + out_b[v]
// B=4 T=256 U=64 D=512 J=640 V=1024.  M = 65536 rows (b,t,u), N=1024, K=640.
//
// ws layout:
//   E  : float [1024][640]            @ 0         (2,621,440 B)   (E then P contiguous)
//   P  : float [ 256][640]            @ 2,621,440 (  655,360 B)
//   Wb : bf16 blocked [4][10][16384]  @ 3,276,800 (1,310,720 B)  pre-swizzled 256x64 blocks

typedef __attribute__((ext_vector_type(8))) __bf16 bf16x8;
typedef __attribute__((ext_vector_type(4))) float f32x4;

// XOR swizzle within a [row][64] bf16 tile (row stride 128B).
__device__ __forceinline__ int swz(int row, int kElem) {
  return (row << 6) + (kElem ^ ((row & 7) << 3));
}

__device__ __forceinline__ float fast_tanh(float x) {
  float e = __builtin_amdgcn_exp2f(x * 2.88539008177793f);  // e^(2x)
  return 1.0f - 2.0f * __builtin_amdgcn_rcpf(e + 1.0f);
}

__device__ __forceinline__ void gload_lds16(const void* g, void* l) {
  __builtin_amdgcn_global_load_lds(
      (const __attribute__((address_space(1))) void*)g,
      (__attribute__((address_space(3))) void*)l, 16, 0, 0);
}

// ---------------------------------------------------------------------------
// proj tile: C[mt*128..][nt*128..] = A[128][512] . W[128][512]^T + bias
// 256 threads, tile 128x128, BK=64, N=640 K=512 fixed.
// ---------------------------------------------------------------------------
__device__ void proj_tile(const float* __restrict__ A, const float* __restrict__ W,
                          const float* __restrict__ bias, float* __restrict__ C,
                          int mt, int nt, __bf16* As, __bf16* Bs)
{
  const int tid  = threadIdx.x;
  const int r = tid & 127, half = tid >> 7;
  const int lane = tid & 63, wv = tid >> 6;
  const int wm = wv >> 1, wn = wv & 1;

  const float* arow = A + (size_t)(mt * 128 + r) * 512 + half * 32;
  const float* wrow = W + (size_t)(nt * 128 + r) * 512 + half * 32;

  f32x4 acc[4][4] = {};

  for (int k0 = 0; k0 < 512; k0 += 64) {
#pragma unroll
    for (int s = 0; s < 4; ++s) {
      f32x4 a0 = *(const f32x4*)(arow + k0 + s * 8);
      f32x4 a1 = *(const f32x4*)(arow + k0 + s * 8 + 4);
      f32x4 w0 = *(const f32x4*)(wrow + k0 + s * 8);
      f32x4 w1 = *(const f32x4*)(wrow + k0 + s * 8 + 4);
      bf16x8 za, zw;
#pragma unroll
      for (int j = 0; j < 4; ++j) {
        za[j] = (__bf16)a0[j]; za[4 + j] = (__bf16)a1[j];
        zw[j] = (__bf16)w0[j]; zw[4 + j] = (__bf16)w1[j];
      }
      const int kk = half * 32 + s * 8;
      *(bf16x8*)&As[swz(r, kk)] = za;
      *(bf16x8*)&Bs[swz(r, kk)] = zw;
    }
    __syncthreads();
#pragma unroll
    for (int kk = 0; kk < 2; ++kk) {
      bf16x8 af[4], bfr[4];
#pragma unroll
      for (int i = 0; i < 4; ++i) {
        af[i]  = *(const bf16x8*)&As[swz(wm * 64 + i * 16 + (lane & 15), kk * 32 + (lane >> 4) * 8)];
        bfr[i] = *(const bf16x8*)&Bs[swz(wn * 64 + i * 16 + (lane & 15), kk * 32 + (lane >> 4) * 8)];
      }
#pragma unroll
      for (int mi = 0; mi < 4; ++mi)
#pragma unroll
        for (int ni = 0; ni < 4; ++ni)
          acc[mi][ni] = __builtin_amdgcn_mfma_f32_16x16x32_bf16(af[mi], bfr[ni], acc[mi][ni], 0, 0, 0);
    }
    __syncthreads();
  }

  const int rowbase = mt * 128 + wm * 64;
  const int colbase = nt * 128 + wn * 64;
#pragma unroll
  for (int ni = 0; ni < 4; ++ni) {
    const int col = colbase + ni * 16 + (lane & 15);
    const float bb = bias[col];
#pragma unroll
    for (int mi = 0; mi < 4; ++mi) {
      const int row = rowbase + mi * 16 + (lane >> 4) * 4;
#pragma unroll
      for (int rg = 0; rg < 4; ++rg)
        C[(size_t)(row + rg) * 640 + col] = acc[mi][ni][rg] + bb;
    }
  }
}

// ---------------------------------------------------------------------------
// prep: blocks 0..39 enc-proj, 40..49 pred-proj, 50..369 out_w conversion.
// out_w fp32 [1024][640] -> bf16 blocked [nb(4)][kb(10)][16384], pre-swizzled.
// ---------------------------------------------------------------------------
__global__ __launch_bounds__(256) void prep_kernel(
    const float* __restrict__ enc,  const float* __restrict__ enc_w,  const float* __restrict__ enc_b,
    const float* __restrict__ pred, const float* __restrict__ pred_w, const float* __restrict__ pred_b,
    const float* __restrict__ out_w,
    float* __restrict__ E, float* __restrict__ P, __bf16* __restrict__ Wb)
{
  __shared__ __align__(16) __bf16 As[128 * 64];
  __shared__ __align__(16) __bf16 Bs[128 * 64];
  const int bid = blockIdx.x;
  if (bid < 40) {
    proj_tile(enc, enc_w, enc_b, E, bid / 5, bid % 5, As, Bs);
  } else if (bid < 50) {
    proj_tile(pred, pred_w, pred_b, P, (bid - 40) / 5, (bid - 40) % 5, As, Bs);
  } else {
    const int gid = (bid - 50) * 256 + threadIdx.x;  // 81920 total (1024*80)
    const int v  = gid / 80;
    const int j8 = gid % 80;
    f32x4 w0 = *(const f32x4*)(out_w + (size_t)v * 640 + j8 * 8);
    f32x4 w1 = *(const f32x4*)(out_w + (size_t)v * 640 + j8 * 8 + 4);
    bf16x8 z;
#pragma unroll
    for (int j = 0; j < 4; ++j) { z[j] = (__bf16)w0[j]; z[4 + j] = (__bf16)w1[j]; }
    const int nb = v >> 8, rr = v & 255;
    const int kb = j8 >> 3, kk = (j8 & 7) * 8;
    *(bf16x8*)(Wb + ((size_t)(nb * 10 + kb) << 14) + swz(rr, kk)) = z;
  }
}

// ---------------------------------------------------------------------------
// main: fused tanh(E+P) x Wb GEMM.
// grid = 512*4; block tile 128(M) x 256(N), BK=64, 512 threads = 8 waves (2Mx4N),
// each wave 64x64 via 4x4 frags of mfma_f32_16x16x32_bf16.
// M row = ((b*256+t)*64+u); a 128-row tile = fixed b, 2 t's, all 64 u's.
// B staged via global_load_lds (Wb pre-swizzled -> linear copy IS swizzled layout).
// ---------------------------------------------------------------------------
__global__ __launch_bounds__(512, 4) void joiner_main(
    const float* __restrict__ E, const float* __restrict__ P,
    const __bf16* __restrict__ Wb, const float* __restrict__ outb,
    float* __restrict__ out)
{
  __shared__ __align__(16) __bf16 As[128 * 64];   // 16 KB
  __shared__ __align__(16) __bf16 Bs[256 * 64];   // 32 KB
  const int tid = threadIdx.x;
  const int nt = blockIdx.x & 3;
  const int mt = blockIdx.x >> 2;
  const int row0 = mt << 7;
  const int b  = row0 >> 14;
  const int t0 = (row0 >> 6) & 255;
  const int r = tid & 127, q = tid >> 7;          // A staging: row r, k-groups q*8, q*8+32
  const int lane = tid & 63, wv = tid >> 6;
  const int wm = wv >> 2, wn = wv & 3;            // 2 x 4 wave grid

  const float* ep = E + (size_t)((b << 8) + t0 + (r >> 6)) * 640;
  const float* pp = P + (size_t)((b << 6) + (r & 63)) * 640;
  const __bf16* wsrc = Wb + ((size_t)(nt * 10) << 14);

  f32x4 acc[4][4] = {};

  for (int kt = 0; kt < 10; ++kt) {
    const int k0 = kt << 6;
    // --- stage B: 32KB linear copy of pre-swizzled block via global_load_lds ---
#pragma unroll
    for (int c = 0; c < 4; ++c) {
      const int off = c * 4096 + wv * 512;        // bf16 elems; +lane*8 implicit on LDS side
      gload_lds16(wsrc + (kt << 14) + off + lane * 8, &Bs[off]);
    }
    // --- stage A: z = tanh(E+P), fp32 -> bf16, swizzled ds_write ---
#pragma unroll
    for (int g = 0; g < 2; ++g) {
      const int kk = g * 32 + q * 8;
      f32x4 e0 = *(const f32x4*)(ep + k0 + kk);
      f32x4 e1 = *(const f32x4*)(ep + k0 + kk + 4);
      f32x4 p0 = *(const f32x4*)(pp + k0 + kk);
      f32x4 p1 = *(const f32x4*)(pp + k0 + kk + 4);
      bf16x8 z;
#pragma unroll
      for (int j = 0; j < 4; ++j) {
        z[j]     = (__bf16)fast_tanh(e0[j] + p0[j]);
        z[4 + j] = (__bf16)fast_tanh(e1[j] + p1[j]);
      }
      *(bf16x8*)&As[swz(r, kk)] = z;
    }
    __syncthreads();
#pragma unroll
    for (int kk = 0; kk < 2; ++kk) {
      bf16x8 af[4], bfr[4];
#pragma unroll
      for (int i = 0; i < 4; ++i) {
        af[i]  = *(const bf16x8*)&As[swz(wm * 64 + i * 16 + (lane & 15), kk * 32 + (lane >> 4) * 8)];
        bfr[i] = *(const bf16x8*)&Bs[swz(wn * 64 + i * 16 + (lane & 15), kk * 32 + (lane >> 4) * 8)];
      }
#pragma unroll
      for (int mi = 0; mi < 4; ++mi)
#pragma unroll
        for (int ni = 0; ni < 4; ++ni)
          acc[mi][ni] = __builtin_amdgcn_mfma_f32_16x16x32_bf16(af[mi], bfr[ni], acc[mi][ni], 0, 0, 0);
    }
    __syncthreads();
  }

  const int rowbase = row0 + wm * 64;
  const int colbase = (nt << 8) + wn * 64;
#pragma unroll
  for (int ni = 0; ni < 4; ++ni) {
    const int col = colbase + ni * 16 + (lane & 15);
    const float bb = outb[col];
#pragma unroll
    for (int mi = 0; mi < 4; ++mi) {
      const int row = rowbase + mi * 16 + (lane >> 4) * 4;
#pragma unroll
      for (int rg = 0; rg < 4; ++rg)
        out[(size_t)(row + rg) * 1024 + col] = acc[mi][ni][rg] + bb;
    }
  }
}

extern "C" void kernel_launch(void* const* d_in, const int* in_sizes, int n_in,
                              void* d_out, int out_size, void* d_ws, size_t ws_size,
                              hipStream_t stream) {
  const float* enc    = (const float*)d_in[0];
  const float* pred   = (const float*)d_in[1];
  const float* enc_w  = (const float*)d_in[2];
  const float* enc_b  = (const float*)d_in[3];
  const float* pred_w = (const float*)d_in[4];
  const float* pred_b = (const float*)d_in[5];
  const float* out_w  = (const float*)d_in[6];
  const float* out_b  = (const float*)d_in[7];
  float* out = (float*)d_out;

  char* ws = (char*)d_ws;
  float*  E  = (float*)(ws);                  // 1024*640 f32
  float*  P  = (float*)(ws + 2621440);        //  256*640 f32
  __bf16* Wb = (__bf16*)(ws + 3276800);       // 4*10*16384 bf16, pre-swizzled

  prep_kernel<<<dim3(370), dim3(256), 0, stream>>>(
      enc, enc_w, enc_b, pred, pred_w, pred_b, out_w, E, P, Wb);
  joiner_main<<<dim3(512 * 4), dim3(512), 0, stream>>>(E, P, Wb, out_b, out);
}